// Round 2
// baseline (1674.180 us; speedup 1.0000x reference)
//
#include <hip/hip_runtime.h>
#include <hip/hip_bf16.h>

#define HH 64      // hidden
#define TT 256     // seq len
#define NB 1024    // batch
#define GG 256     // 4*H gates
#define DD0 5      // layer-0 input dim
#define DD1 128    // layer-1 input dim (2*H)

__device__ __forceinline__ float sigf(float x) { return 1.0f / (1.0f + __expf(-x)); }
__device__ __forceinline__ float tanh_fast(float x) { return 2.0f / (1.0f + __expf(-2.0f * x)) - 1.0f; }

// ---------------------------------------------------------------------------
// Layer 0: one (row, dir) per block, 256 threads, thread j = gate j.
// Weights (5 + 64 floats) live in registers; ~100 VGPR -> 16 waves/CU.
// grid = 2048 blocks -> 4 blocks/CU resident (barriers overlap across blocks).
// ---------------------------------------------------------------------------
template <bool BF16OUT>
__launch_bounds__(256, 4)
__global__ void lstm_l0(const float* __restrict__ x,
                        const float* __restrict__ w_ih_f, const float* __restrict__ w_hh_f,
                        const float* __restrict__ b_ih_f, const float* __restrict__ b_hh_f,
                        const float* __restrict__ w_ih_r, const float* __restrict__ w_hh_r,
                        const float* __restrict__ b_ih_r, const float* __restrict__ b_hh_r,
                        void* __restrict__ out0) {
    const int tid = threadIdx.x;
    const int row = blockIdx.x >> 1;
    const int dir = blockIdx.x & 1;

    const float* w_ih = dir ? w_ih_r : w_ih_f;
    const float* w_hh = dir ? w_hh_r : w_hh_f;
    const float* b_ih = dir ? b_ih_r : b_ih_f;
    const float* b_hh = dir ? b_hh_r : b_hh_f;

    __shared__ __align__(16) float xs[TT * DD0];  // 5 KB: this row's x, all t
    __shared__ __align__(16) float hs[HH];
    __shared__ __align__(16) float gs[GG];
    __shared__ __align__(16) float bs[GG];

    for (int i = tid; i < TT * DD0; i += 256)
        xs[i] = x[(size_t)row * TT * DD0 + i];
    if (tid < HH) hs[tid] = 0.0f;
    bs[tid] = b_ih[tid] + b_hh[tid];

    float wih[DD0];
#pragma unroll
    for (int d = 0; d < DD0; ++d) wih[d] = w_ih[tid * DD0 + d];
    float whh[HH];
#pragma unroll
    for (int k = 0; k < HH; ++k) whh[k] = w_hh[tid * HH + k];

    float c = 0.0f;
    __syncthreads();

    for (int t = 0; t < TT; ++t) {
        const int tt = dir ? (TT - 1 - t) : t;
        // gate phase: all LDS reads are wave-uniform broadcasts
        float a0 = 0.f, a1 = 0.f, a2 = 0.f, a3 = 0.f;
#pragma unroll
        for (int d = 0; d < DD0; ++d) a0 += wih[d] * xs[tt * DD0 + d];
        const float4* h4 = (const float4*)hs;
#pragma unroll
        for (int kk = 0; kk < 16; ++kk) {
            float4 hv = h4[kk];
            a0 += whh[4 * kk + 0] * hv.x;
            a1 += whh[4 * kk + 1] * hv.y;
            a2 += whh[4 * kk + 2] * hv.z;
            a3 += whh[4 * kk + 3] * hv.w;
        }
        gs[tid] = (a0 + a1) + (a2 + a3);
        __syncthreads();
        if (tid < HH) {
            const int u = tid;
            float gi = gs[u] + bs[u];
            float gf = gs[u + 64] + bs[u + 64];
            float gc = gs[u + 128] + bs[u + 128];
            float go = gs[u + 192] + bs[u + 192];
            c = sigf(gf) * c + sigf(gi) * tanh_fast(gc);
            float h = sigf(go) * tanh_fast(c);
            hs[u] = h;
            size_t oidx = (size_t)row * TT * DD1 + (size_t)tt * DD1 + dir * HH + u;
            if (BF16OUT) ((__hip_bfloat16*)out0)[oidx] = __float2bfloat16(h);
            else         ((float*)out0)[oidx] = h;
        }
        __syncthreads();
    }
}

// ---------------------------------------------------------------------------
// Layer 1 forward: one row per block, 1024 threads. Thread (q = tid>>8,
// g = tid&255) computes quarter q of gate g's dot product: 32 input-k +
// 16 h-k = 48 weight floats in registers (~80 VGPR -> 16 waves/CU).
// Partials reduced via LDS gs[4][256]; wave 1 prefetches next input tile.
// ---------------------------------------------------------------------------
template <bool BF16IN>
__launch_bounds__(1024, 4)
__global__ void lstm_l1(const void* __restrict__ in0,
                        const float* __restrict__ w_ih, const float* __restrict__ w_hh,
                        const float* __restrict__ b_ih, const float* __restrict__ b_hh,
                        float* __restrict__ h_last) {
    const int tid = threadIdx.x;
    const int row = blockIdx.x;
    const int q   = tid >> 8;
    const int g   = tid & 255;

    __shared__ __align__(16) float ins[2][DD1];  // double-buffered input tile
    __shared__ __align__(16) float hs[HH];
    __shared__ __align__(16) float gs[4][GG];
    __shared__ __align__(16) float bs[GG];

    float wih[32];
#pragma unroll
    for (int k = 0; k < 32; ++k) wih[k] = w_ih[g * DD1 + q * 32 + k];
    float whh[16];
#pragma unroll
    for (int k = 0; k < 16; ++k) whh[k] = w_hh[g * HH + q * 16 + k];

    if (tid < GG) bs[tid] = b_ih[tid] + b_hh[tid];
    if (tid < HH) hs[tid] = 0.0f;

    const bool pfw = (tid >= 64 && tid < 128);  // wave 1 = prefetch wave
    const int  pj  = tid - 64;

    auto load_in = [&](int t, float2* v) {
        size_t base = ((size_t)row * TT + t) * DD1 + pj * 2;
        if (BF16IN) {
            const __hip_bfloat16* p = (const __hip_bfloat16*)in0 + base;
            v->x = __bfloat162float(p[0]);
            v->y = __bfloat162float(p[1]);
        } else {
            *v = *(const float2*)((const float*)in0 + base);
        }
    };

    if (pfw) {  // stage t = 0
        float2 v;
        load_in(0, &v);
        ((float2*)ins[0])[pj] = v;
    }
    float c = 0.0f;
    __syncthreads();

    for (int t = 0; t < TT; ++t) {
        const int cur = t & 1;
        float2 pf;
        if (pfw && t + 1 < TT) load_in(t + 1, &pf);  // issue early

        // gate phase: uniform LDS broadcasts + register weights
        float a0 = 0.f, a1 = 0.f, a2 = 0.f, a3 = 0.f;
        const float4* in4 = (const float4*)&ins[cur][q * 32];
#pragma unroll
        for (int kk = 0; kk < 8; ++kk) {
            float4 iv = in4[kk];
            a0 += wih[4 * kk + 0] * iv.x;
            a1 += wih[4 * kk + 1] * iv.y;
            a2 += wih[4 * kk + 2] * iv.z;
            a3 += wih[4 * kk + 3] * iv.w;
        }
        const float4* h4 = (const float4*)&hs[q * 16];
#pragma unroll
        for (int kk = 0; kk < 4; ++kk) {
            float4 hv = h4[kk];
            a0 += whh[4 * kk + 0] * hv.x;
            a1 += whh[4 * kk + 1] * hv.y;
            a2 += whh[4 * kk + 2] * hv.z;
            a3 += whh[4 * kk + 3] * hv.w;
        }
        gs[q][g] = (a0 + a1) + (a2 + a3);
        __syncthreads();

        if (tid < HH) {
            const int u = tid;
            float gi = gs[0][u]       + gs[1][u]       + gs[2][u]       + gs[3][u]       + bs[u];
            float gf = gs[0][u + 64]  + gs[1][u + 64]  + gs[2][u + 64]  + gs[3][u + 64]  + bs[u + 64];
            float gc = gs[0][u + 128] + gs[1][u + 128] + gs[2][u + 128] + gs[3][u + 128] + bs[u + 128];
            float go = gs[0][u + 192] + gs[1][u + 192] + gs[2][u + 192] + gs[3][u + 192] + bs[u + 192];
            c = sigf(gf) * c + sigf(gi) * tanh_fast(gc);
            float h = sigf(go) * tanh_fast(c);
            hs[u] = h;
            if (t == TT - 1) h_last[(size_t)row * HH + u] = h;
        }
        if (pfw && t + 1 < TT) ((float2*)ins[cur ^ 1])[pj] = pf;
        __syncthreads();
    }
}

// ---------------------------------------------------------------------------
// Tail: layer-1 backward is ONE step at t = T-1 from zero state (h0=0 kills
// the w_hh term), then FC. grid = 1024 blocks (one per batch), 256 threads.
// ---------------------------------------------------------------------------
template <bool BF16IN>
__global__ void lstm_tail(const void* __restrict__ in0,
                          const float* __restrict__ h1f,
                          const float* __restrict__ w_ih_r,
                          const float* __restrict__ b_ih_r, const float* __restrict__ b_hh_r,
                          const float* __restrict__ fc_w, const float* __restrict__ fc_b,
                          float* __restrict__ out) {
    const int b   = blockIdx.x;
    const int tid = threadIdx.x;
    __shared__ __align__(16) float insl[DD1];
    __shared__ __align__(16) float hb[HH];
    __shared__ __align__(16) float gsh[GG];

    if (tid < DD1) {
        size_t base = ((size_t)b * TT + (TT - 1)) * DD1 + tid;
        insl[tid] = BF16IN ? __bfloat162float(((const __hip_bfloat16*)in0)[base])
                           : ((const float*)in0)[base];
    }
    __syncthreads();

    float a0 = b_ih_r[tid] + b_hh_r[tid], a1 = 0.f, a2 = 0.f, a3 = 0.f;
    const float4* in4 = (const float4*)insl;
#pragma unroll
    for (int kk = 0; kk < 32; ++kk) {
        float4 iv = in4[kk];
        float4 wv = *(const float4*)&w_ih_r[tid * DD1 + 4 * kk];
        a0 += wv.x * iv.x;
        a1 += wv.y * iv.y;
        a2 += wv.z * iv.z;
        a3 += wv.w * iv.w;
    }
    gsh[tid] = (a0 + a1) + (a2 + a3);
    __syncthreads();

    if (tid < HH) {
        float gi = gsh[tid], gc = gsh[tid + 128], go = gsh[tid + 192];
        float cc = sigf(gi) * tanh_fast(gc);  // c_prev = 0
        hb[tid] = sigf(go) * tanh_fast(cc);
    }
    __syncthreads();

    if (tid < 64) {
        float p = fc_w[tid] * h1f[(size_t)b * HH + tid] + fc_w[HH + tid] * hb[tid];
#pragma unroll
        for (int off = 32; off; off >>= 1) p += __shfl_xor(p, off);
        if (tid == 0) out[b] = p + fc_b[0];
    }
}

// ---------------------------------------------------------------------------
extern "C" void kernel_launch(void* const* d_in, const int* in_sizes, int n_in,
                              void* d_out, int out_size, void* d_ws, size_t ws_size,
                              hipStream_t stream) {
    const float* x = (const float*)d_in[0];
    // l0 fwd: 1..4, l0 rev: 5..8, l1 fwd: 9..12, l1 rev: 13..16, fc: 17,18
    const size_t out0_f32_bytes = (size_t)NB * TT * DD1 * sizeof(float);  // 134 MB
    const size_t hlast_bytes    = (size_t)NB * HH * sizeof(float);

    const bool bf16 = (ws_size < out0_f32_bytes + hlast_bytes);
    char* ws = (char*)d_ws;
    void* out0 = (void*)ws;
    const size_t out0_bytes = bf16 ? out0_f32_bytes / 2 : out0_f32_bytes;
    float* h1f = (float*)(ws + out0_bytes);

    if (!bf16) {
        lstm_l0<false><<<2048, 256, 0, stream>>>(
            x, (const float*)d_in[1], (const float*)d_in[2], (const float*)d_in[3], (const float*)d_in[4],
            (const float*)d_in[5], (const float*)d_in[6], (const float*)d_in[7], (const float*)d_in[8], out0);
        lstm_l1<false><<<1024, 1024, 0, stream>>>(
            out0, (const float*)d_in[9], (const float*)d_in[10], (const float*)d_in[11], (const float*)d_in[12], h1f);
        lstm_tail<false><<<1024, 256, 0, stream>>>(
            out0, h1f, (const float*)d_in[13], (const float*)d_in[15], (const float*)d_in[16],
            (const float*)d_in[17], (const float*)d_in[18], (float*)d_out);
    } else {
        lstm_l0<true><<<2048, 256, 0, stream>>>(
            x, (const float*)d_in[1], (const float*)d_in[2], (const float*)d_in[3], (const float*)d_in[4],
            (const float*)d_in[5], (const float*)d_in[6], (const float*)d_in[7], (const float*)d_in[8], out0);
        lstm_l1<true><<<1024, 1024, 0, stream>>>(
            out0, (const float*)d_in[9], (const float*)d_in[10], (const float*)d_in[11], (const float*)d_in[12], h1f);
        lstm_tail<true><<<1024, 256, 0, stream>>>(
            out0, h1f, (const float*)d_in[13], (const float*)d_in[15], (const float*)d_in[16],
            (const float*)d_in[17], (const float*)d_in[18], (float*)d_out);
    }
}